// Round 1
// 545.266 us; speedup vs baseline: 1.1689x; 1.1689x over previous
//
#include <hip/hip_runtime.h>
#include <hip/hip_bf16.h>

using bf16 = __hip_bfloat16;
typedef __bf16 bf16x8 __attribute__((ext_vector_type(8)));
typedef float f32x4 __attribute__((ext_vector_type(4)));

#define MFMA16(A, B, C) __builtin_amdgcn_mfma_f32_16x16x32_bf16((A), (B), (C), 0, 0, 0)

__device__ __forceinline__ void store_elem(bf16* p, float v) { *p = __float2bfloat16(v); }
__device__ __forceinline__ void store_elem(float* p, float v) { *p = v; }

__device__ __forceinline__ unsigned short f2bu(float x) {
    bf16 t = __float2bfloat16(x);
    return *(unsigned short*)&t;
}

// async global->LDS 16B per lane; LDS dest = wave-uniform base + lane*16.
__device__ __forceinline__ void async_cp16(const bf16* g, bf16* l) {
    __builtin_amdgcn_global_load_lds(
        (const __attribute__((address_space(1))) void*)g,
        (__attribute__((address_space(3))) void*)l, 16, 0, 0);
}

// ---------------------------------------------------------------------------
__global__ void cvt_fp32_bf16(const float* __restrict__ src, bf16* __restrict__ dst) {
    int i = (blockIdx.x * 256 + threadIdx.x) * 4;
    float4 v = *(const float4*)(src + i);
    bf16 o[4] = {__float2bfloat16(v.x), __float2bfloat16(v.y),
                 __float2bfloat16(v.z), __float2bfloat16(v.w)};
    *(uint2*)(dst + i) = *(const uint2*)o;
}

// ---------------------------------------------------------------------------
__global__ void wtrans(const float* __restrict__ src, bf16* __restrict__ dst,
                       int K, int N) {
    __shared__ bf16 t[32][33];
    int n0 = blockIdx.x * 32, k0 = blockIdx.y * 32;
    #pragma unroll
    for (int i = 0; i < 4; ++i) {
        int r = threadIdx.y + i * 8;
        t[r][threadIdx.x] = __float2bfloat16(src[(size_t)(k0 + r) * N + n0 + threadIdx.x]);
    }
    __syncthreads();
    #pragma unroll
    for (int i = 0; i < 4; ++i) {
        int r = threadIdx.y + i * 8;
        dst[(size_t)(n0 + r) * K + k0 + threadIdx.x] = t[threadIdx.x][r];
    }
}

__global__ void zerofill(bf16* __restrict__ p) {
    p[blockIdx.x * 256 + threadIdx.x] = __float2bfloat16(0.0f);
}

// ---------------------------------------------------------------------------
// GEMM: C[M][N] = A[M][K] @ Bt[N][K]^T. global_load_lds staging (m97 pattern).
// ---------------------------------------------------------------------------
template <typename CT>
__global__ __launch_bounds__(256) void gemm_bt(
    const bf16* __restrict__ A, int lda,
    const bf16* __restrict__ Bt, int ldb,
    CT* __restrict__ C, int ldc, int K) {
    __shared__ bf16 As[128 * 32];
    __shared__ bf16 Bs[128 * 32];
    const int m0 = blockIdx.y * 128;
    const int n0 = blockIdx.x * 128;
    const int tid = threadIdx.x;
    const int lane = tid & 63;
    const int wave = tid >> 6;
    const int wm = (wave >> 1) * 64;
    const int wn = (wave & 1) * 64;
    const int lr = lane & 15;
    const int lq = lane >> 4;
    const int sr = tid >> 2;
    const int sc = (tid & 3) * 8;
    const int wbase = wave * 512;

    f32x4 acc[4][4] = {};

    for (int k0 = 0; k0 < K; k0 += 32) {
        __syncthreads();
        async_cp16(A + (size_t)(m0 + sr) * lda + k0 + sc, As + wbase);
        async_cp16(A + (size_t)(m0 + sr + 64) * lda + k0 + sc, As + 2048 + wbase);
        async_cp16(Bt + (size_t)(n0 + sr) * ldb + k0 + sc, Bs + wbase);
        async_cp16(Bt + (size_t)(n0 + sr + 64) * ldb + k0 + sc, Bs + 2048 + wbase);
        __syncthreads();
        bf16x8 af[4], bfr[4];
        #pragma unroll
        for (int t = 0; t < 4; ++t) {
            af[t]  = *(const bf16x8*)(As + (wm + t * 16 + lr) * 32 + lq * 8);
            bfr[t] = *(const bf16x8*)(Bs + (wn + t * 16 + lr) * 32 + lq * 8);
        }
        #pragma unroll
        for (int mt = 0; mt < 4; ++mt)
            #pragma unroll
            for (int nt = 0; nt < 4; ++nt)
                acc[mt][nt] = MFMA16(af[mt], bfr[nt], acc[mt][nt]);
    }
    #pragma unroll
    for (int mt = 0; mt < 4; ++mt)
        #pragma unroll
        for (int nt = 0; nt < 4; ++nt)
            #pragma unroll
            for (int r = 0; r < 4; ++r) {
                int row = m0 + wm + mt * 16 + lq * 4 + r;
                int col = n0 + wn + nt * 16 + lr;
                store_elem(C + (size_t)row * ldc + col, acc[mt][nt][r]);
            }
}

// ---------------------------------------------------------------------------
// kv GEMM, split epilogue: k_nope -> kbuf, v -> vT (transposed). grid (32,32).
// ---------------------------------------------------------------------------
__global__ __launch_bounds__(256) void gemm_kv(
    const bf16* __restrict__ A, int lda,
    const bf16* __restrict__ Bt, int ldb,
    bf16* __restrict__ kbuf, bf16* __restrict__ vT, int K) {
    __shared__ bf16 As[128 * 32];
    __shared__ bf16 Bs[128 * 32];
    const int m0 = blockIdx.y * 128;
    const int n0 = blockIdx.x * 128;
    const int tid = threadIdx.x;
    const int lane = tid & 63;
    const int wave = tid >> 6;
    const int wm = (wave >> 1) * 64;
    const int wn = (wave & 1) * 64;
    const int lr = lane & 15;
    const int lq = lane >> 4;
    const int sr = tid >> 2;
    const int sc = (tid & 3) * 8;
    const int wbase = wave * 512;

    f32x4 acc[4][4] = {};

    for (int k0 = 0; k0 < K; k0 += 32) {
        __syncthreads();
        async_cp16(A + (size_t)(m0 + sr) * lda + k0 + sc, As + wbase);
        async_cp16(A + (size_t)(m0 + sr + 64) * lda + k0 + sc, As + 2048 + wbase);
        async_cp16(Bt + (size_t)(n0 + sr) * ldb + k0 + sc, Bs + wbase);
        async_cp16(Bt + (size_t)(n0 + sr + 64) * ldb + k0 + sc, Bs + 2048 + wbase);
        __syncthreads();
        bf16x8 af[4], bfr[4];
        #pragma unroll
        for (int t = 0; t < 4; ++t) {
            af[t]  = *(const bf16x8*)(As + (wm + t * 16 + lr) * 32 + lq * 8);
            bfr[t] = *(const bf16x8*)(Bs + (wn + t * 16 + lr) * 32 + lq * 8);
        }
        #pragma unroll
        for (int mt = 0; mt < 4; ++mt)
            #pragma unroll
            for (int nt = 0; nt < 4; ++nt)
                acc[mt][nt] = MFMA16(af[mt], bfr[nt], acc[mt][nt]);
    }
    #pragma unroll
    for (int mt = 0; mt < 4; ++mt)
        #pragma unroll
        for (int nt = 0; nt < 4; ++nt) {
            int colbase = n0 + wn + nt * 16;
            int h = colbase >> 8;
            int rr = (colbase & 255) + lr;
            #pragma unroll
            for (int r = 0; r < 4; ++r) {
                int row = m0 + wm + mt * 16 + lq * 4 + r;
                bf16 val = __float2bfloat16(acc[mt][nt][r]);
                if (rr < 128) {
                    kbuf[(size_t)row * 2048 + h * 128 + rr] = val;
                } else {
                    int dv = rr - 128;
                    int b = row >> 11, s = row & 2047;
                    vT[((size_t)((b * 16 + h) * 128 + dv)) * 2048 + s] = val;
                }
            }
        }
}

// ---------------------------------------------------------------------------
__global__ void rope_kernel(bf16* __restrict__ XW) {
    int v = blockIdx.x;
    int row = blockIdx.y * 4 + threadIdx.y;
    int i = threadIdx.x;
    int s = row & 2047;
    int cbase = (v < 16) ? v * 192 + 128 : 3072;
    size_t base = (size_t)row * 3712 + cbase;
    float xi = __bfloat162float(XW[base + i]);
    float xp = __shfl_xor(xi, 32);
    int j = i & 31;
    float inv = exp2f(-(float)j * (13.287712379549449f / 32.0f));
    float ang = (float)s * inv;
    float c = cosf(ang), sn = sinf(ang);
    float res = (i < 32) ? (xi * c - xp * sn) : (xi * c + xp * sn);
    XW[base + i] = __float2bfloat16(res);
}

// ---------------------------------------------------------------------------
// Flash attention, barrier-free rewrite.
//
// Decomposition: q-unit u in [0,64) = 32 q rows (rows 32u..32u+31) of one
// (b,h). Unit u needs nt(u) = u/2+1 key-tiles of 64. Pair (u, 63-u) = exactly
// 33 tiles. Each WAVE handles one key-chunk half of a pair: chunk0 = tiles
// [0, ceil(nt/2)), chunk1 = rest, for both units of the pair. => every wave
// does exactly 16-17 tiles, deterministically balanced, no dispatch-order
// assumptions. 512 blocks x 4 waves = 2048 waves, ALL co-resident
// (LDS 18.4KB, launch_bounds(256,2) => 8 waves/CU).
//
// No __syncthreads anywhere: K-nope/K-rope/V fragments are read per-lane
// directly from L2 (per-bh working set ~1.3MB; bid%8 <-> bh%8 clusters 4 bh
// per XCD-L2). LDS holds only the per-wave P round-trip + O-transpose
// epilogue (in-wave lgkmcnt ordering only).
//
// Partials merge flash-style: each chunk stores O/l (bf16) + s = m + log2(l)
// (one float per (q,h,chunk)); merge weights w_i = exp2(s_i - max).
// chunk0 -> attn_out (in-place merge), chunk1 -> opart.
// ---------------------------------------------------------------------------
__global__ __launch_bounds__(256, 2) void attn_kernel(
    const bf16* __restrict__ XW, const bf16* __restrict__ kbuf,
    const bf16* __restrict__ vT, bf16* __restrict__ attn_out,
    bf16* __restrict__ opart, float* __restrict__ mlbuf) {
    const int bid = blockIdx.x;
    const int half = bid >> 8;          // key-chunk index
    const int rr = bid & 255;
    const int bh = rr & 31;             // bid%8 == bh%8 -> XCD clustering
    const int pg = rr >> 5;
    const int b = bh >> 4, h = bh & 15;
    const int tid = threadIdx.x;
    const int wave = tid >> 6;
    const int lane = tid & 63;
    const int lr = lane & 15, lq = lane >> 4;
    const int ub = pg * 4 + wave;       // base unit in [0,32)

    __shared__ bf16 Pm[4 * 32 * 72];    // per-wave 32x72 P; 16x136 Tr epilogue
    bf16* Pw = Pm + wave * (32 * 72);

    const bf16* xwb = XW + (size_t)b * 2048 * 3712;
    const bf16* kb  = kbuf + (size_t)b * 2048 * 2048 + h * 128;
    const bf16* rp  = xwb + 3072;       // k_rope columns
    const bf16* vTb = vT + (size_t)bh * 128 * 2048;

    const float sc2 = 0.07216878364870323f * 1.4426950408889634f;  // scale*log2e

    #pragma unroll 1
    for (int ph = 0; ph < 2; ++ph) {
        const int u = ph ? (63 - ub) : ub;
        const int qw = u * 32;
        const int nt = (u >> 1) + 1;
        const int hnt = (nt + 1) >> 1;
        const int t0 = half ? hnt : 0;
        const int t1 = half ? nt : hnt;

        // Q B-frags: [n=q(lane&15)][k=lq*8..], 2 nf groups x 6 feature chunks
        bf16x8 qf[2][6];
        #pragma unroll
        for (int nf = 0; nf < 2; ++nf) {
            size_t ro = (size_t)(qw + nf * 16 + lr) * 3712 + h * 192;
            #pragma unroll
            for (int c = 0; c < 6; ++c)
                qf[nf][c] = *(const bf16x8*)(xwb + ro + c * 32 + lq * 8);
        }

        f32x4 o[2][8] = {};      // O^T: [nf][dt], col=q, row=dv
        float m_i[2], l_i[2];
        m_i[0] = m_i[1] = -1e30f;
        l_i[0] = l_i[1] = 0.0f;

        for (int t = t0; t < t1; ++t) {
            const int n0 = t * 64;
            // ---- S^T = K Q^T: 24 direct L2 b128 loads, 48 MFMAs ----
            f32x4 st[4][2] = {};   // [mt(key)][nf(q)]
            __builtin_amdgcn_s_setprio(1);
            #pragma unroll
            for (int c = 0; c < 6; ++c) {
                #pragma unroll
                for (int mt = 0; mt < 4; ++mt) {
                    bf16x8 kf = (c < 4)
                        ? *(const bf16x8*)(kb + (size_t)(n0 + mt * 16 + lr) * 2048 + c * 32 + lq * 8)
                        : *(const bf16x8*)(rp + (size_t)(n0 + mt * 16 + lr) * 3712 + (c - 4) * 32 + lq * 8);
                    st[mt][0] = MFMA16(kf, qf[0][c], st[mt][0]);
                    st[mt][1] = MFMA16(kf, qf[1][c], st[mt][1]);
                }
            }
            __builtin_amdgcn_s_setprio(0);
            // ---- vectorized online softmax (per nf: 1 q per lane, 16 keys) ----
            #pragma unroll
            for (int nf = 0; nf < 2; ++nf) {
                int q = qw + nf * 16 + lr;
                f32x4 a[4];
                #pragma unroll
                for (int mt = 0; mt < 4; ++mt)
                    #pragma unroll
                    for (int r = 0; r < 4; ++r) a[mt][r] = st[mt][nf][r] * sc2;
                if (n0 + 63 > qw + nf * 16) {   // wave-uniform: diagonal tile only
                    #pragma unroll
                    for (int mt = 0; mt < 4; ++mt)
                        #pragma unroll
                        for (int r = 0; r < 4; ++r) {
                            int kid = n0 + mt * 16 + lq * 4 + r;
                            if (kid > q) a[mt][r] = -1e30f;
                        }
                }
                f32x4 m4 = a[0];
                #pragma unroll
                for (int mt = 1; mt < 4; ++mt)
                    #pragma unroll
                    for (int r = 0; r < 4; ++r) m4[r] = fmaxf(m4[r], a[mt][r]);
                float vm = fmaxf(fmaxf(m4[0], m4[1]), fmaxf(m4[2], m4[3]));
                vm = fmaxf(vm, __shfl_xor(vm, 16));
                vm = fmaxf(vm, __shfl_xor(vm, 32));
                float mnew = fmaxf(m_i[nf], vm);
                float alpha = exp2f(m_i[nf] - mnew);
                m_i[nf] = mnew;
                float ps = 0.0f;
                #pragma unroll
                for (int mt = 0; mt < 4; ++mt) {
                    unsigned short pk[4];
                    #pragma unroll
                    for (int r = 0; r < 4; ++r) {
                        float p = exp2f(a[mt][r] - mnew);
                        ps += p;
                        pk[r] = f2bu(p);
                    }
                    *(uint2*)((unsigned short*)Pw + (nf * 16 + lr) * 72 + mt * 16 + lq * 4) =
                        *(uint2*)pk;
                }
                ps += __shfl_xor(ps, 16);
                ps += __shfl_xor(ps, 32);
                l_i[nf] = l_i[nf] * alpha + ps;
                #pragma unroll
                for (int dt = 0; dt < 8; ++dt)
                    #pragma unroll
                    for (int r = 0; r < 4; ++r) o[nf][dt][r] *= alpha;
            }
            // in-wave LDS RAW
            __asm__ volatile("s_waitcnt lgkmcnt(0)" ::: "memory");
            bf16x8 ptf[2][2];
            #pragma unroll
            for (int nf = 0; nf < 2; ++nf)
                #pragma unroll
                for (int kt = 0; kt < 2; ++kt)
                    ptf[nf][kt] = *(const bf16x8*)(Pw + (nf * 16 + lr) * 72 + kt * 32 + lq * 8);
            // ---- O^T += V^T P: 16 direct L2 b128 loads, 32 MFMAs ----
            __builtin_amdgcn_s_setprio(1);
            #pragma unroll
            for (int kt = 0; kt < 2; ++kt)
                #pragma unroll
                for (int dt = 0; dt < 8; ++dt) {
                    bf16x8 vf = *(const bf16x8*)(vTb + (size_t)(dt * 16 + lr) * 2048 + n0 + kt * 32 + lq * 8);
                    o[0][dt] = MFMA16(vf, ptf[0][kt], o[0][dt]);
                    o[1][dt] = MFMA16(vf, ptf[1][kt], o[1][dt]);
                }
            __builtin_amdgcn_s_setprio(0);
        }

        // ---- epilogue: O^T -> O via per-wave LDS transpose, partial store ----
        #pragma unroll
        for (int nf = 0; nf < 2; ++nf) {
            float l = l_i[nf];
            float wsc = (l > 0.0f) ? (1.0f / l) : 0.0f;
            float sst = (l > 0.0f) ? (m_i[nf] + log2f(l)) : -1e30f;
            __asm__ volatile("s_waitcnt lgkmcnt(0)" ::: "memory");
            #pragma unroll
            for (int dt = 0; dt < 8; ++dt) {
                unsigned short pk[4];
                #pragma unroll
                for (int r = 0; r < 4; ++r) pk[r] = f2bu(o[nf][dt][r] * wsc);
                *(uint2*)((unsigned short*)Pw + lr * 136 + dt * 16 + lq * 4) = *(uint2*)pk;
            }
            __asm__ volatile("s_waitcnt lgkmcnt(0)" ::: "memory");
            int ql = lane >> 2, cs = (lane & 3) * 32;
            int qrow = qw + nf * 16 + ql;
            uint4 d[4];
            #pragma unroll
            for (int k = 0; k < 4; ++k)
                d[k] = *(const uint4*)(Pw + ql * 136 + cs + k * 8);
            bf16* dst = (half ? opart : attn_out) +
                        (size_t)(b * 2048 + qrow) * 2048 + h * 128 + cs;
            #pragma unroll
            for (int k = 0; k < 4; ++k) *(uint4*)(dst + k * 8) = d[k];
            if (lane < 16) {
                int q2 = qw + nf * 16 + lane;
                mlbuf[((size_t)(b * 2048 + q2) * 16 + h) * 2 + half] = sst;
            }
        }
    }
}

// ---------------------------------------------------------------------------
// Merge the two key-chunk partials for every q row. s = m + log2(l) per chunk
// (log2 domain); partials are already normalized by their own l.
// ---------------------------------------------------------------------------
__global__ void attn_merge(const bf16* __restrict__ opart,
                           const float* __restrict__ mlbuf,
                           bf16* __restrict__ attn_out) {
    int bs = blockIdx.x;            // b*2048 + s
    int h = blockIdx.y * 2 + threadIdx.y;
    int tx = threadIdx.x;
    const float* mlp = mlbuf + ((size_t)bs * 16 + h) * 2;
    float s0 = mlp[0], s1 = mlp[1];
    size_t off = (size_t)bs * 2048 + h * 128 + tx;
    float o0 = __bfloat162float(attn_out[off]);
    float o1 = __bfloat162float(opart[off]);
    float m = fmaxf(s0, s1);
    float w0 = exp2f(s0 - m);
    float w1 = exp2f(s1 - m);
    float v = (o0 * w0 + o1 * w1) / (w0 + w1);
    attn_out[off] = __float2bfloat16(v);
}

// ---------------------------------------------------------------------------
extern "C" void kernel_launch(void* const* d_in, const int* in_sizes, int n_in,
                              void* d_out, int out_size, void* d_ws, size_t ws_size,
                              hipStream_t stream) {
    const float* x    = (const float*)d_in[0];
    const float* Wq   = (const float*)d_in[1];
    const float* Wdkv = (const float*)d_in[2];
    const float* Wkr  = (const float*)d_in[3];
    const float* Wukv = (const float*)d_in[4];
    const float* Wo   = (const float*)d_in[5];
    float* out = (float*)d_out;

    // Workspace layout (98,041,856 bytes), time-sliced aliasing.
    char* ws = (char*)d_ws;
    bf16* XW       = (bf16*)(ws);
    bf16* kbuf     = (bf16*)(ws + 30408704);
    bf16* vT       = (bf16*)(ws + 47185920);
    bf16* attn_out = (bf16*)(ws + 63963136);
    bf16* opart    = (bf16*)(ws + 80740352);
    float* mlbuf   = (float*)(ws + 97517568);   // 4096*16*2 floats = 512KB
    bf16* xb       = (bf16*)(ws + 30408704);  // alias kbuf
    bf16* WcatT    = (bf16*)(ws + 47185920);  // alias vT
    bf16* WukvT    = (bf16*)(ws + 63963136);  // alias attn_out
    bf16* WoT      = (bf16*)(ws + 47185920);  // alias vT (after attn)

    dim3 tb(32, 8);
    cvt_fp32_bf16<<<8192, 256, 0, stream>>>(x, xb);
    wtrans<<<dim3(96, 64), tb, 0, stream>>>(Wq, WcatT, 2048, 3072);
    wtrans<<<dim3(2, 64), tb, 0, stream>>>(Wkr, WcatT + (size_t)3072 * 2048, 2048, 64);
    wtrans<<<dim3(16, 64), tb, 0, stream>>>(Wdkv, WcatT + (size_t)3136 * 2048, 2048, 512);
    zerofill<<<512, 256, 0, stream>>>(WcatT + (size_t)3648 * 2048);
    wtrans<<<dim3(128, 16), tb, 0, stream>>>(Wukv, WukvT, 512, 4096);

    gemm_bt<bf16><<<dim3(29, 32), 256, 0, stream>>>(xb, 2048, WcatT, 2048, XW, 3712, 2048);
    rope_kernel<<<dim3(17, 1024), dim3(64, 4), 0, stream>>>(XW);
    gemm_kv<<<dim3(32, 32), 256, 0, stream>>>(XW + 3136, 3712, WukvT, 512, kbuf, vT, 512);
    attn_kernel<<<dim3(512), 256, 0, stream>>>(XW, kbuf, vT, attn_out, opart, mlbuf);
    attn_merge<<<dim3(4096, 8), dim3(128, 2), 0, stream>>>(opart, mlbuf, attn_out);
    wtrans<<<dim3(64, 64), tb, 0, stream>>>(Wo, WoT, 2048, 2048);
    gemm_bt<float><<<dim3(16, 32), 256, 0, stream>>>(attn_out, 2048, WoT, 2048, out, 2048, 2048);
}

// Round 2
// 544.468 us; speedup vs baseline: 1.1706x; 1.0015x over previous
//
#include <hip/hip_runtime.h>
#include <hip/hip_bf16.h>

using bf16 = __hip_bfloat16;
typedef __bf16 bf16x8 __attribute__((ext_vector_type(8)));
typedef float f32x4 __attribute__((ext_vector_type(4)));

#define MFMA16(A, B, C) __builtin_amdgcn_mfma_f32_16x16x32_bf16((A), (B), (C), 0, 0, 0)

__device__ __forceinline__ void store_elem(bf16* p, float v) { *p = __float2bfloat16(v); }
__device__ __forceinline__ void store_elem(float* p, float v) { *p = v; }

__device__ __forceinline__ unsigned short f2bu(float x) {
    bf16 t = __float2bfloat16(x);
    return *(unsigned short*)&t;
}

// async global->LDS 16B per lane; LDS dest = wave-uniform base + lane*16.
__device__ __forceinline__ void async_cp16(const bf16* g, bf16* l) {
    __builtin_amdgcn_global_load_lds(
        (const __attribute__((address_space(1))) void*)g,
        (__attribute__((address_space(3))) void*)l, 16, 0, 0);
}

// ---------------------------------------------------------------------------
__global__ void cvt_fp32_bf16(const float* __restrict__ src, bf16* __restrict__ dst) {
    int i = (blockIdx.x * 256 + threadIdx.x) * 4;
    float4 v = *(const float4*)(src + i);
    bf16 o[4] = {__float2bfloat16(v.x), __float2bfloat16(v.y),
                 __float2bfloat16(v.z), __float2bfloat16(v.w)};
    *(uint2*)(dst + i) = *(const uint2*)o;
}

// ---------------------------------------------------------------------------
__global__ void wtrans(const float* __restrict__ src, bf16* __restrict__ dst,
                       int K, int N) {
    __shared__ bf16 t[32][33];
    int n0 = blockIdx.x * 32, k0 = blockIdx.y * 32;
    #pragma unroll
    for (int i = 0; i < 4; ++i) {
        int r = threadIdx.y + i * 8;
        t[r][threadIdx.x] = __float2bfloat16(src[(size_t)(k0 + r) * N + n0 + threadIdx.x]);
    }
    __syncthreads();
    #pragma unroll
    for (int i = 0; i < 4; ++i) {
        int r = threadIdx.y + i * 8;
        dst[(size_t)(n0 + r) * K + k0 + threadIdx.x] = t[threadIdx.x][r];
    }
}

__global__ void zerofill(bf16* __restrict__ p) {
    p[blockIdx.x * 256 + threadIdx.x] = __float2bfloat16(0.0f);
}

// ---------------------------------------------------------------------------
// GEMM: C[M][N] = A[M][K] @ Bt[N][K]^T. global_load_lds staging (m97 pattern).
// ---------------------------------------------------------------------------
template <typename CT>
__global__ __launch_bounds__(256) void gemm_bt(
    const bf16* __restrict__ A, int lda,
    const bf16* __restrict__ Bt, int ldb,
    CT* __restrict__ C, int ldc, int K) {
    __shared__ bf16 As[128 * 32];
    __shared__ bf16 Bs[128 * 32];
    const int m0 = blockIdx.y * 128;
    const int n0 = blockIdx.x * 128;
    const int tid = threadIdx.x;
    const int lane = tid & 63;
    const int wave = tid >> 6;
    const int wm = (wave >> 1) * 64;
    const int wn = (wave & 1) * 64;
    const int lr = lane & 15;
    const int lq = lane >> 4;
    const int sr = tid >> 2;
    const int sc = (tid & 3) * 8;
    const int wbase = wave * 512;

    f32x4 acc[4][4] = {};

    for (int k0 = 0; k0 < K; k0 += 32) {
        __syncthreads();
        async_cp16(A + (size_t)(m0 + sr) * lda + k0 + sc, As + wbase);
        async_cp16(A + (size_t)(m0 + sr + 64) * lda + k0 + sc, As + 2048 + wbase);
        async_cp16(Bt + (size_t)(n0 + sr) * ldb + k0 + sc, Bs + wbase);
        async_cp16(Bt + (size_t)(n0 + sr + 64) * ldb + k0 + sc, Bs + 2048 + wbase);
        __syncthreads();
        bf16x8 af[4], bfr[4];
        #pragma unroll
        for (int t = 0; t < 4; ++t) {
            af[t]  = *(const bf16x8*)(As + (wm + t * 16 + lr) * 32 + lq * 8);
            bfr[t] = *(const bf16x8*)(Bs + (wn + t * 16 + lr) * 32 + lq * 8);
        }
        #pragma unroll
        for (int mt = 0; mt < 4; ++mt)
            #pragma unroll
            for (int nt = 0; nt < 4; ++nt)
                acc[mt][nt] = MFMA16(af[mt], bfr[nt], acc[mt][nt]);
    }
    #pragma unroll
    for (int mt = 0; mt < 4; ++mt)
        #pragma unroll
        for (int nt = 0; nt < 4; ++nt)
            #pragma unroll
            for (int r = 0; r < 4; ++r) {
                int row = m0 + wm + mt * 16 + lq * 4 + r;
                int col = n0 + wn + nt * 16 + lr;
                store_elem(C + (size_t)row * ldc + col, acc[mt][nt][r]);
            }
}

// ---------------------------------------------------------------------------
// kv GEMM, split epilogue: k_nope -> kbuf, v -> vT (transposed). grid (32,32).
// ---------------------------------------------------------------------------
__global__ __launch_bounds__(256) void gemm_kv(
    const bf16* __restrict__ A, int lda,
    const bf16* __restrict__ Bt, int ldb,
    bf16* __restrict__ kbuf, bf16* __restrict__ vT, int K) {
    __shared__ bf16 As[128 * 32];
    __shared__ bf16 Bs[128 * 32];
    const int m0 = blockIdx.y * 128;
    const int n0 = blockIdx.x * 128;
    const int tid = threadIdx.x;
    const int lane = tid & 63;
    const int wave = tid >> 6;
    const int wm = (wave >> 1) * 64;
    const int wn = (wave & 1) * 64;
    const int lr = lane & 15;
    const int lq = lane >> 4;
    const int sr = tid >> 2;
    const int sc = (tid & 3) * 8;
    const int wbase = wave * 512;

    f32x4 acc[4][4] = {};

    for (int k0 = 0; k0 < K; k0 += 32) {
        __syncthreads();
        async_cp16(A + (size_t)(m0 + sr) * lda + k0 + sc, As + wbase);
        async_cp16(A + (size_t)(m0 + sr + 64) * lda + k0 + sc, As + 2048 + wbase);
        async_cp16(Bt + (size_t)(n0 + sr) * ldb + k0 + sc, Bs + wbase);
        async_cp16(Bt + (size_t)(n0 + sr + 64) * ldb + k0 + sc, Bs + 2048 + wbase);
        __syncthreads();
        bf16x8 af[4], bfr[4];
        #pragma unroll
        for (int t = 0; t < 4; ++t) {
            af[t]  = *(const bf16x8*)(As + (wm + t * 16 + lr) * 32 + lq * 8);
            bfr[t] = *(const bf16x8*)(Bs + (wn + t * 16 + lr) * 32 + lq * 8);
        }
        #pragma unroll
        for (int mt = 0; mt < 4; ++mt)
            #pragma unroll
            for (int nt = 0; nt < 4; ++nt)
                acc[mt][nt] = MFMA16(af[mt], bfr[nt], acc[mt][nt]);
    }
    #pragma unroll
    for (int mt = 0; mt < 4; ++mt)
        #pragma unroll
        for (int nt = 0; nt < 4; ++nt) {
            int colbase = n0 + wn + nt * 16;
            int h = colbase >> 8;
            int rr = (colbase & 255) + lr;
            #pragma unroll
            for (int r = 0; r < 4; ++r) {
                int row = m0 + wm + mt * 16 + lq * 4 + r;
                bf16 val = __float2bfloat16(acc[mt][nt][r]);
                if (rr < 128) {
                    kbuf[(size_t)row * 2048 + h * 128 + rr] = val;
                } else {
                    int dv = rr - 128;
                    int b = row >> 11, s = row & 2047;
                    vT[((size_t)((b * 16 + h) * 128 + dv)) * 2048 + s] = val;
                }
            }
        }
}

// ---------------------------------------------------------------------------
__global__ void rope_kernel(bf16* __restrict__ XW) {
    int v = blockIdx.x;
    int row = blockIdx.y * 4 + threadIdx.y;
    int i = threadIdx.x;
    int s = row & 2047;
    int cbase = (v < 16) ? v * 192 + 128 : 3072;
    size_t base = (size_t)row * 3712 + cbase;
    float xi = __bfloat162float(XW[base + i]);
    float xp = __shfl_xor(xi, 32);
    int j = i & 31;
    float inv = exp2f(-(float)j * (13.287712379549449f / 32.0f));
    float ang = (float)s * inv;
    float c = cosf(ang), sn = sinf(ang);
    float res = (i < 32) ? (xi * c - xp * sn) : (xi * c + xp * sn);
    XW[base + i] = __float2bfloat16(res);
}

// ---------------------------------------------------------------------------
// Flash attention, barrier-free. Per R1 counters the kernel is latency-bound
// (all pipes <25%); R2 removes the serially-exposed V-load latency:
//  - V fragments prefetched into registers ABOVE the lgkmcnt asm barrier
//    (the "memory" clobber was pinning them after softmax -> ~400 exposed
//    cycles/tile). +64 VGPR, fine at 2 waves/SIMD (256 budget).
//  - T13 defer-max: skip O-rescale unless __any(vm > m + 8) (wave-uniform).
//  - sc2 scale folded into exp2 via fma (max tracked in raw domain).
// ---------------------------------------------------------------------------
__global__ __launch_bounds__(256, 2) void attn_kernel(
    const bf16* __restrict__ XW, const bf16* __restrict__ kbuf,
    const bf16* __restrict__ vT, bf16* __restrict__ attn_out,
    bf16* __restrict__ opart, float* __restrict__ mlbuf) {
    const int bid = blockIdx.x;
    const int half = bid >> 8;          // key-chunk index
    const int rr = bid & 255;
    const int bh = rr & 31;             // bid%8 == bh%8 -> XCD clustering
    const int pg = rr >> 5;
    const int b = bh >> 4, h = bh & 15;
    const int tid = threadIdx.x;
    const int wave = tid >> 6;
    const int lane = tid & 63;
    const int lr = lane & 15, lq = lane >> 4;
    const int ub = pg * 4 + wave;       // base unit in [0,32)

    __shared__ bf16 Pm[4 * 32 * 72];    // per-wave 32x72 P; 16x136 Tr epilogue
    bf16* Pw = Pm + wave * (32 * 72);

    const bf16* xwb = XW + (size_t)b * 2048 * 3712;
    const bf16* kb  = kbuf + (size_t)b * 2048 * 2048 + h * 128;
    const bf16* rp  = xwb + 3072;       // k_rope columns
    const bf16* vTb = vT + (size_t)bh * 128 * 2048;

    const float sc2 = 0.07216878364870323f * 1.4426950408889634f;  // scale*log2e

    #pragma unroll 1
    for (int ph = 0; ph < 2; ++ph) {
        const int u = ph ? (63 - ub) : ub;
        const int qw = u * 32;
        const int nt = (u >> 1) + 1;
        const int hnt = (nt + 1) >> 1;
        const int t0 = half ? hnt : 0;
        const int t1 = half ? nt : hnt;

        // Q B-frags: [n=q(lane&15)][k=lq*8..], 2 nf groups x 6 feature chunks
        bf16x8 qf[2][6];
        #pragma unroll
        for (int nf = 0; nf < 2; ++nf) {
            size_t ro = (size_t)(qw + nf * 16 + lr) * 3712 + h * 192;
            #pragma unroll
            for (int c = 0; c < 6; ++c)
                qf[nf][c] = *(const bf16x8*)(xwb + ro + c * 32 + lq * 8);
        }

        f32x4 o[2][8] = {};      // O^T: [nf][dt], col=q, row=dv
        float m_i[2], l_i[2];
        m_i[0] = m_i[1] = -1e30f;
        l_i[0] = l_i[1] = 0.0f;

        for (int t = t0; t < t1; ++t) {
            const int n0 = t * 64;
            // ---- S^T = K Q^T: 24 direct L2 b128 loads, 48 MFMAs ----
            f32x4 st[4][2] = {};   // [mt(key)][nf(q)]
            __builtin_amdgcn_s_setprio(1);
            #pragma unroll
            for (int c = 0; c < 6; ++c) {
                #pragma unroll
                for (int mt = 0; mt < 4; ++mt) {
                    bf16x8 kf = (c < 4)
                        ? *(const bf16x8*)(kb + (size_t)(n0 + mt * 16 + lr) * 2048 + c * 32 + lq * 8)
                        : *(const bf16x8*)(rp + (size_t)(n0 + mt * 16 + lr) * 3712 + (c - 4) * 32 + lq * 8);
                    st[mt][0] = MFMA16(kf, qf[0][c], st[mt][0]);
                    st[mt][1] = MFMA16(kf, qf[1][c], st[mt][1]);
                }
            }
            __builtin_amdgcn_s_setprio(0);

            // ---- V prefetch: issue ABOVE the asm barrier so the loads'
            // latency hides under softmax (they were pinned below before) ----
            bf16x8 vf[2][8];
            #pragma unroll
            for (int kt = 0; kt < 2; ++kt)
                #pragma unroll
                for (int dt = 0; dt < 8; ++dt)
                    vf[kt][dt] = *(const bf16x8*)(vTb + (size_t)(dt * 16 + lr) * 2048 + n0 + kt * 32 + lq * 8);

            // ---- online softmax, raw-domain max, fma-folded scale ----
            #pragma unroll
            for (int nf = 0; nf < 2; ++nf) {
                int q = qw + nf * 16 + lr;
                f32x4 a[4];
                #pragma unroll
                for (int mt = 0; mt < 4; ++mt) a[mt] = st[mt][nf];
                if (n0 + 63 > qw + nf * 16) {   // wave-uniform: diagonal tile only
                    #pragma unroll
                    for (int mt = 0; mt < 4; ++mt)
                        #pragma unroll
                        for (int r = 0; r < 4; ++r) {
                            int kid = n0 + mt * 16 + lq * 4 + r;
                            if (kid > q) a[mt][r] = -1e30f;
                        }
                }
                f32x4 m4 = a[0];
                #pragma unroll
                for (int mt = 1; mt < 4; ++mt)
                    #pragma unroll
                    for (int r = 0; r < 4; ++r) m4[r] = fmaxf(m4[r], a[mt][r]);
                float vm = fmaxf(fmaxf(m4[0], m4[1]), fmaxf(m4[2], m4[3]));
                vm = fmaxf(vm, __shfl_xor(vm, 16));
                vm = fmaxf(vm, __shfl_xor(vm, 32));
                vm *= sc2;
                // T13 defer-max: only rescale when the max actually grows.
                if (__any(vm > m_i[nf] + 8.0f)) {
                    float mnew = fmaxf(m_i[nf], vm);
                    float alpha = exp2f(m_i[nf] - mnew);
                    m_i[nf] = mnew;
                    l_i[nf] *= alpha;
                    #pragma unroll
                    for (int dt = 0; dt < 8; ++dt)
                        #pragma unroll
                        for (int r = 0; r < 4; ++r) o[nf][dt][r] *= alpha;
                }
                float mi = m_i[nf];
                float ps = 0.0f;
                #pragma unroll
                for (int mt = 0; mt < 4; ++mt) {
                    unsigned short pk[4];
                    #pragma unroll
                    for (int r = 0; r < 4; ++r) {
                        float p = exp2f(fmaf(a[mt][r], sc2, -mi));
                        ps += p;
                        pk[r] = f2bu(p);
                    }
                    *(uint2*)((unsigned short*)Pw + (nf * 16 + lr) * 72 + mt * 16 + lq * 4) =
                        *(uint2*)pk;
                }
                ps += __shfl_xor(ps, 16);
                ps += __shfl_xor(ps, 32);
                l_i[nf] += ps;
            }
            // in-wave LDS RAW
            __asm__ volatile("s_waitcnt lgkmcnt(0)" ::: "memory");
            bf16x8 ptf[2][2];
            #pragma unroll
            for (int nf = 0; nf < 2; ++nf)
                #pragma unroll
                for (int kt = 0; kt < 2; ++kt)
                    ptf[nf][kt] = *(const bf16x8*)(Pw + (nf * 16 + lr) * 72 + kt * 32 + lq * 8);
            // ---- O^T += V^T P from prefetched registers: 32 MFMAs ----
            __builtin_amdgcn_s_setprio(1);
            #pragma unroll
            for (int kt = 0; kt < 2; ++kt)
                #pragma unroll
                for (int dt = 0; dt < 8; ++dt) {
                    o[0][dt] = MFMA16(vf[kt][dt], ptf[0][kt], o[0][dt]);
                    o[1][dt] = MFMA16(vf[kt][dt], ptf[1][kt], o[1][dt]);
                }
            __builtin_amdgcn_s_setprio(0);
        }

        // ---- epilogue: O^T -> O via per-wave LDS transpose, partial store ----
        #pragma unroll
        for (int nf = 0; nf < 2; ++nf) {
            float l = l_i[nf];
            float wsc = (l > 0.0f) ? (1.0f / l) : 0.0f;
            float sst = (l > 0.0f) ? (m_i[nf] + log2f(l)) : -1e30f;
            __asm__ volatile("s_waitcnt lgkmcnt(0)" ::: "memory");
            #pragma unroll
            for (int dt = 0; dt < 8; ++dt) {
                unsigned short pk[4];
                #pragma unroll
                for (int r = 0; r < 4; ++r) pk[r] = f2bu(o[nf][dt][r] * wsc);
                *(uint2*)((unsigned short*)Pw + lr * 136 + dt * 16 + lq * 4) = *(uint2*)pk;
            }
            __asm__ volatile("s_waitcnt lgkmcnt(0)" ::: "memory");
            int ql = lane >> 2, cs = (lane & 3) * 32;
            int qrow = qw + nf * 16 + ql;
            uint4 d[4];
            #pragma unroll
            for (int k = 0; k < 4; ++k)
                d[k] = *(const uint4*)(Pw + ql * 136 + cs + k * 8);
            bf16* dst = (half ? opart : attn_out) +
                        (size_t)(b * 2048 + qrow) * 2048 + h * 128 + cs;
            #pragma unroll
            for (int k = 0; k < 4; ++k) *(uint4*)(dst + k * 8) = d[k];
            if (lane < 16) {
                int q2 = qw + nf * 16 + lane;
                mlbuf[((size_t)(b * 2048 + q2) * 16 + h) * 2 + half] = sst;
            }
        }
    }
}

// ---------------------------------------------------------------------------
// Merge the two key-chunk partials for every q row. s = m + log2(l) per chunk
// (log2 domain); partials are already normalized by their own l.
// ---------------------------------------------------------------------------
__global__ void attn_merge(const bf16* __restrict__ opart,
                           const float* __restrict__ mlbuf,
                           bf16* __restrict__ attn_out) {
    int bs = blockIdx.x;            // b*2048 + s
    int h = blockIdx.y * 2 + threadIdx.y;
    int tx = threadIdx.x;
    const float* mlp = mlbuf + ((size_t)bs * 16 + h) * 2;
    float s0 = mlp[0], s1 = mlp[1];
    size_t off = (size_t)bs * 2048 + h * 128 + tx;
    float o0 = __bfloat162float(attn_out[off]);
    float o1 = __bfloat162float(opart[off]);
    float m = fmaxf(s0, s1);
    float w0 = exp2f(s0 - m);
    float w1 = exp2f(s1 - m);
    float v = (o0 * w0 + o1 * w1) / (w0 + w1);
    attn_out[off] = __float2bfloat16(v);
}

// ---------------------------------------------------------------------------
extern "C" void kernel_launch(void* const* d_in, const int* in_sizes, int n_in,
                              void* d_out, int out_size, void* d_ws, size_t ws_size,
                              hipStream_t stream) {
    const float* x    = (const float*)d_in[0];
    const float* Wq   = (const float*)d_in[1];
    const float* Wdkv = (const float*)d_in[2];
    const float* Wkr  = (const float*)d_in[3];
    const float* Wukv = (const float*)d_in[4];
    const float* Wo   = (const float*)d_in[5];
    float* out = (float*)d_out;

    // Workspace layout (98,041,856 bytes), time-sliced aliasing.
    char* ws = (char*)d_ws;
    bf16* XW       = (bf16*)(ws);
    bf16* kbuf     = (bf16*)(ws + 30408704);
    bf16* vT       = (bf16*)(ws + 47185920);
    bf16* attn_out = (bf16*)(ws + 63963136);
    bf16* opart    = (bf16*)(ws + 80740352);
    float* mlbuf   = (float*)(ws + 97517568);   // 4096*16*2 floats = 512KB
    bf16* xb       = (bf16*)(ws + 30408704);  // alias kbuf
    bf16* WcatT    = (bf16*)(ws + 47185920);  // alias vT
    bf16* WukvT    = (bf16*)(ws + 63963136);  // alias attn_out
    bf16* WoT      = (bf16*)(ws + 47185920);  // alias vT (after attn)

    dim3 tb(32, 8);
    cvt_fp32_bf16<<<8192, 256, 0, stream>>>(x, xb);
    wtrans<<<dim3(96, 64), tb, 0, stream>>>(Wq, WcatT, 2048, 3072);
    wtrans<<<dim3(2, 64), tb, 0, stream>>>(Wkr, WcatT + (size_t)3072 * 2048, 2048, 64);
    wtrans<<<dim3(16, 64), tb, 0, stream>>>(Wdkv, WcatT + (size_t)3136 * 2048, 2048, 512);
    zerofill<<<512, 256, 0, stream>>>(WcatT + (size_t)3648 * 2048);
    wtrans<<<dim3(128, 16), tb, 0, stream>>>(Wukv, WukvT, 512, 4096);

    gemm_bt<bf16><<<dim3(29, 32), 256, 0, stream>>>(xb, 2048, WcatT, 2048, XW, 3712, 2048);
    rope_kernel<<<dim3(17, 1024), dim3(64, 4), 0, stream>>>(XW);
    gemm_kv<<<dim3(32, 32), 256, 0, stream>>>(XW + 3136, 3712, WukvT, 512, kbuf, vT, 512);
    attn_kernel<<<dim3(512), 256, 0, stream>>>(XW, kbuf, vT, attn_out, opart, mlbuf);
    attn_merge<<<dim3(4096, 8), dim3(128, 2), 0, stream>>>(opart, mlbuf, attn_out);
    wtrans<<<dim3(64, 64), tb, 0, stream>>>(Wo, WoT, 2048, 2048);
    gemm_bt<float><<<dim3(16, 32), 256, 0, stream>>>(attn_out, 2048, WoT, 2048, out, 2048, 2048);
}